// Round 8
// baseline (163.125 us; speedup 1.0000x reference)
//
#include <hip/hip_runtime.h>
#include <hip/hip_bf16.h>

#define BB 2
#define SS 2048
#define DD 1024
#define HH 16
#define KSZ 64

typedef __attribute__((ext_vector_type(8))) short s16x8;   // MFMA A/B frag (8 bf16)
typedef __attribute__((ext_vector_type(4))) short s16x4;   // K=16 MFMA frag (4 bf16)
typedef __attribute__((ext_vector_type(4))) float f32x4;   // MFMA C/D frag
typedef __attribute__((ext_vector_type(8))) unsigned short u16x8;
typedef __attribute__((ext_vector_type(4))) unsigned short u16x4;
typedef __attribute__((ext_vector_type(2))) unsigned int u32x2;
typedef unsigned short u16;

__device__ __forceinline__ u16 bf16rne(float f) {
  unsigned int u = __float_as_uint(f);
  unsigned int r = (u + 0x7FFFu + ((u >> 16) & 1u)) >> 16;
  return (u16)r;
}

// packed f32x2 -> bf16x2 (RNE), no builtin on gfx950 (T12 recipe)
__device__ __forceinline__ unsigned int cvtpk_bf16(float lo, float hi) {
  unsigned int r;
  asm("v_cvt_pk_bf16_f32 %0, %1, %2" : "=v"(r) : "v"(lo), "v"(hi));
  return r;
}

// 16x16x16 bf16 MFMA (K=16): builtin name varies across ROCm; hedge.
#if __has_builtin(__builtin_amdgcn_mfma_f32_16x16x16_bf16)
__device__ __forceinline__ f32x4 mfma16(s16x4 a, s16x4 b, f32x4 c) {
  return __builtin_amdgcn_mfma_f32_16x16x16_bf16(a, b, c, 0, 0, 0);
}
#elif __has_builtin(__builtin_amdgcn_mfma_f32_16x16x16bf16_1k)
__device__ __forceinline__ f32x4 mfma16(s16x4 a, s16x4 b, f32x4 c) {
  return __builtin_amdgcn_mfma_f32_16x16x16bf16_1k(a, b, c, 0, 0, 0);
}
#else
__device__ __forceinline__ f32x4 mfma16(s16x4 a, s16x4 b, f32x4 c) {
  asm("s_nop 1\n\tv_mfma_f32_16x16x16_bf16 %0, %1, %2, %0"
      : "+v"(c) : "v"(a), "v"(b));
  return c;
}
#endif

__device__ __forceinline__ void lds_dma16(const u16* g, u16* l) {
  __builtin_amdgcn_global_load_lds(
      (const __attribute__((address_space(1))) unsigned int*)(const void*)g,
      (__attribute__((address_space(3))) unsigned int*)(void*)l, 16, 0, 0);
}

// ---------------------------------------------------------------------------
// Merged prep (flat grid 2880): [0,2048) cast x->bf16; [2048,2816) transpose
// W->Wt[n][d]; [2816,2880) out-weight permute.
// ---------------------------------------------------------------------------
__global__ __launch_bounds__(256) void prep_all(
    const float* __restrict__ x, const float* __restrict__ Wq,
    const float* __restrict__ Wk, const float* __restrict__ Wv,
    const float* __restrict__ kern, u16* __restrict__ xb,
    u16* __restrict__ Wt, u16* __restrict__ BpT) {
  __shared__ float Ts[64][65];
  const int bid = blockIdx.x;
  const int tid = threadIdx.x;
  if (bid < 2048) {
    int idx = (bid * 256 + tid) * 8;
    float4 a = *(const float4*)(x + idx);
    float4 b = *(const float4*)(x + idx + 4);
    u16x8 v;
    v[0] = bf16rne(a.x); v[1] = bf16rne(a.y); v[2] = bf16rne(a.z); v[3] = bf16rne(a.w);
    v[4] = bf16rne(b.x); v[5] = bf16rne(b.y); v[6] = bf16rne(b.z); v[7] = bf16rne(b.w);
    *(u16x8*)(xb + idx) = v;
  } else if (bid < 2816) {
    const int bx = bid - 2048;
    const int p = bx >> 8, rem = bx & 255;
    const int d0 = (rem & 15) * 64, n0 = (rem >> 4) * 64;
    const float* W = (p == 0) ? Wq : (p == 1) ? Wk : Wv;
    u16* Wo = Wt + (size_t)p * DD * DD;
    #pragma unroll
    for (int i = 0; i < 4; ++i) {
      int f4 = tid + i * 256;
      int r = f4 >> 4, c4 = f4 & 15;
      float4 v = *(const float4*)(W + (size_t)(d0 + r) * DD + n0 + c4 * 4);
      Ts[r][c4 * 4 + 0] = v.x; Ts[r][c4 * 4 + 1] = v.y;
      Ts[r][c4 * 4 + 2] = v.z; Ts[r][c4 * 4 + 3] = v.w;
    }
    __syncthreads();
    #pragma unroll
    for (int i = 0; i < 4; ++i) {
      int ch = tid + i * 256;
      int n = ch >> 4, d4 = ch & 15;
      u16x4 o;
      #pragma unroll
      for (int j = 0; j < 4; ++j) o[j] = bf16rne(Ts[d4 * 4 + j][n]);
      *(u16x4*)(Wo + (size_t)(n0 + n) * DD + d0 + d4 * 4) = o;
    }
  } else {
    const int n = bid - 2816;
    const int k4 = tid * 4;
    u16x4 o;
    #pragma unroll
    for (int j = 0; j < 4; ++j) {
      int kp = k4 + j;
      int h = kp >> 6, k = kp & 63;
      o[j] = bf16rne(kern[(size_t)(k * HH + h) * KSZ + n]);
    }
    *(u16x4*)(BpT + (size_t)n * (HH * KSZ) + k4) = o;
  }
}

// ---------------------------------------------------------------------------
// Proj v5 (R2-verified, 45.3us): C = xb(4096x1024) @ W(1024x1024), bf16 MFMA.
// BK=32, triple-buffered global_load_lds with counted vmcnt.
// ---------------------------------------------------------------------------
__global__ __launch_bounds__(256) void proj_kernel(
    const u16* __restrict__ xb, const u16* __restrict__ Wt,
    u16* __restrict__ qkvT) {
  const int xcd = blockIdx.x & 7;
  const int idx = blockIdx.x >> 3;                 // 0..95
  const int mt = (xcd >> 1) * 8 + (idx & 7);
  const int nt = (xcd & 1) * 4 + ((idx >> 3) & 3);
  const int p  = idx >> 5;                         // 0..2
  const int m0 = mt * 128, n0 = nt * 128;
  const u16* W = Wt + (size_t)p * DD * DD;         // [n][d]
  u16* outp = qkvT + (size_t)p * (BB * HH * SS * KSZ);

  __shared__ __align__(16) unsigned char raw[49152];
  u16* lds = (u16*)raw;
  u16* Cs  = (u16*)raw;            // [128][136] epilogue reuse (34.8 KB)

  const int tid = threadIdx.x;
  const int wave = tid >> 6, lane = tid & 63;
  const int g = lane >> 4, c = lane & 15;
  const int mbase = (wave & 1) * 64, nbase = (wave >> 1) * 64;

  const int lr = lane >> 2, lc = lane & 3;
  const int swz = (lc ^ ((lr >> 1) & 3)) * 8;      // elems
  const int rA0 = (wave * 2 + 0) * 16;             // slab rows
  const int rA1 = (wave * 2 + 1) * 16;
  const u16* srcA0 = xb + (size_t)(m0 + rA0 + lr) * DD + swz;
  const u16* srcA1 = xb + (size_t)(m0 + rA1 + lr) * DD + swz;
  const u16* srcB0 = W  + (size_t)(n0 + rA0 + lr) * DD + swz;
  const u16* srcB1 = W  + (size_t)(n0 + rA1 + lr) * DD + swz;
  const int sl0 = rA0 * 32, sl1 = rA1 * 32;        // LDS slab offsets (u16)

  f32x4 acc[4][4];
  #pragma unroll
  for (int i = 0; i < 4; ++i)
    #pragma unroll
    for (int j = 0; j < 4; ++j) acc[i][j] = {0.f, 0.f, 0.f, 0.f};

  // prologue: tile 0 -> buf0, tile 1 -> buf1 (8 DMAs in flight)
  {
    u16* A0 = lds;                u16* B0 = lds + 4096;
    u16* A1 = lds + 8192;         u16* B1 = lds + 8192 + 4096;
    lds_dma16(srcA0, A0 + sl0);       lds_dma16(srcA1, A0 + sl1);
    lds_dma16(srcB0, B0 + sl0);       lds_dma16(srcB1, B0 + sl1);
    lds_dma16(srcA0 + 32, A1 + sl0);  lds_dma16(srcA1 + 32, A1 + sl1);
    lds_dma16(srcB0 + 32, B1 + sl0);  lds_dma16(srcB1 + 32, B1 + sl1);
  }

  const int jsw = (c >> 1) & 3;                    // frag-read swizzle term
  int cr = 0;                                      // t % 3
  #pragma unroll 1
  for (int t = 0; t < 31; ++t) {
    asm volatile("s_waitcnt vmcnt(4)" ::: "memory");
    __builtin_amdgcn_s_barrier();
    __builtin_amdgcn_sched_barrier(0);
    if (t <= 29) {
      const int st = cr ? cr - 1 : 2;              // (t+2) % 3
      const int ko = (t + 2) * 32;
      u16* An = lds + st * 8192;
      u16* Bn = An + 4096;
      lds_dma16(srcA0 + ko, An + sl0);  lds_dma16(srcA1 + ko, An + sl1);
      lds_dma16(srcB0 + ko, Bn + sl0);  lds_dma16(srcB1 + ko, Bn + sl1);
    }
    u16* Ac = lds + cr * 8192;
    u16* Bc = Ac + 4096;
    s16x8 af[4], bfr[4];
    #pragma unroll
    for (int mf = 0; mf < 4; ++mf)
      af[mf] = *(const s16x8*)&Ac[(mbase + mf * 16 + c) * 32 + ((g ^ jsw) * 8)];
    #pragma unroll
    for (int nf = 0; nf < 4; ++nf)
      bfr[nf] = *(const s16x8*)&Bc[(nbase + nf * 16 + c) * 32 + ((g ^ jsw) * 8)];
    #pragma unroll
    for (int mf = 0; mf < 4; ++mf)
      #pragma unroll
      for (int nf = 0; nf < 4; ++nf)
        acc[mf][nf] = __builtin_amdgcn_mfma_f32_16x16x32_bf16(
            af[mf], bfr[nf], acc[mf][nf], 0, 0, 0);
    cr = (cr >= 2) ? 0 : cr + 1;
  }
  asm volatile("s_waitcnt vmcnt(0)" ::: "memory");
  __builtin_amdgcn_s_barrier();
  __builtin_amdgcn_sched_barrier(0);
  {
    u16* Ac = lds + cr * 8192;
    u16* Bc = Ac + 4096;
    s16x8 af[4], bfr[4];
    #pragma unroll
    for (int mf = 0; mf < 4; ++mf)
      af[mf] = *(const s16x8*)&Ac[(mbase + mf * 16 + c) * 32 + ((g ^ jsw) * 8)];
    #pragma unroll
    for (int nf = 0; nf < 4; ++nf)
      bfr[nf] = *(const s16x8*)&Bc[(nbase + nf * 16 + c) * 32 + ((g ^ jsw) * 8)];
    #pragma unroll
    for (int mf = 0; mf < 4; ++mf)
      #pragma unroll
      for (int nf = 0; nf < 4; ++nf)
        acc[mf][nf] = __builtin_amdgcn_mfma_f32_16x16x32_bf16(
            af[mf], bfr[nf], acc[mf][nf], 0, 0, 0);
  }
  __syncthreads();   // all frag reads done before Cs alias reuse

  const float cscale = (p == 0) ? 0.125f * 1.44269504f : 1.0f;
  #pragma unroll
  for (int mf = 0; mf < 4; ++mf)
    #pragma unroll
    for (int nf = 0; nf < 4; ++nf)
      #pragma unroll
      for (int r = 0; r < 4; ++r)
        Cs[(mbase + mf * 16 + g * 4 + r) * 136 + nbase + nf * 16 + c] =
            bf16rne(acc[mf][nf][r] * cscale);
  __syncthreads();
  const int b = m0 >> 11;
  if (p < 2) {
    int hh = tid >> 4, si = tid & 15;
    #pragma unroll
    for (int i = 0; i < 8; ++i) {
      int row = i * 16 + si;
      int s = (m0 + row) & 2047;
      u16x8 v;
      #pragma unroll
      for (int kp = 0; kp < 8; ++kp) v[kp] = Cs[row * 136 + kp * 16 + hh];
      *(u16x8*)(outp + ((size_t)(b * HH + hh) * SS + s) * KSZ + (n0 >> 4)) = v;
    }
  } else {
    const int s0 = m0 & 2047;
    #pragma unroll
    for (int i = 0; i < 8; ++i) {
      int chunk = tid + i * 256;
      int colid = chunk >> 4;
      int hh = colid >> 3, kp = colid & 7;
      int s8 = chunk & 15;
      u16x8 v;
      #pragma unroll
      for (int j = 0; j < 8; ++j) v[j] = Cs[(s8 * 8 + j) * 136 + kp * 16 + hh];
      *(u16x8*)(outp + ((size_t)(b * HH + hh) * KSZ + (n0 >> 4) + kp) * SS +
                s0 + s8 * 8) = v;
    }
  }
}

// ---------------------------------------------------------------------------
// Attention v11: KVBLK=128 = two v10-style 64-key sub-tiles PER BARRIER.
// (1) barrier count halves (34 -> ~17.5 avg); (2) sub1's QK MFMA chain is
// independent of sub0's PV chain -> compiler interleaves QK(sub1) under
// exp2/PV(sub0) (T15 mechanism, in-wave, zero extra state). Inner body,
// swizzles, in-register P (v10), mask, epilogue all unchanged per sub-tile.
// LDS = [2dbuf][2sub] x (Ks 8K + Vt 8K) = 64 KB -> 2 blocks/CU (R2-R6:
// attn is occupancy-insensitive, so the drop from 4 is safe).
// Sub1 skipped (wave-uniform) when 2t+1 > it. Quad dispatch balanced:
// NT sums to 34 per co-resident {x,15-x,16+x,31-x}.
// ---------------------------------------------------------------------------
__global__ __launch_bounds__(256, 2) void attn_kernel(
    const u16* __restrict__ qkvT, u16* __restrict__ headsB) {
  const int bid = blockIdx.x;
  const int hb = bid & 31;
  const int u  = bid >> 5;                               // 0..31
  const int x  = u & 7, w = u >> 3;
  const int it = (w == 0) ? x : (w == 1) ? 15 - x : (w == 2) ? 16 + x : 31 - x;
  const int h = hb & 15, b = hb >> 4;
  const size_t plane = (size_t)(b * HH + h) * SS * KSZ;
  const size_t PSZ = (size_t)BB * HH * SS * KSZ;
  const u16* Qg = qkvT + plane;            // [s][k], pre-scaled 0.125*log2e
  const u16* Kg = qkvT + PSZ + plane;      // [s][k]
  const u16* Vg = qkvT + 2 * PSZ + plane;  // [k][s]

  __shared__ u16 Ks[2][2][64 * 64];   // [dbuf][sub][key][d], XOR chunk swizzle
  __shared__ u16 Vt[2][2][64 * 64];   // [dbuf][sub][d][key], XOR chunk swizzle

  const int tid = threadIdx.x;
  const int lane = tid & 63;
  const int g = lane >> 4, c = lane & 15;
  const int wq0 = (tid >> 6) * 16;
  const int sr = tid >> 3, sc = tid & 7;
  const int soA = sr * 64 + ((sc ^ (sr & 7)) * 8);   // (sr+32)&7 == sr&7
  const int soB = soA + 32 * 64;

  const int NT = (it >> 1) + 1;            // 128-key super-tiles

  // Q fragments: loop-invariant, straight from global
  s16x8 bq0 = *(const s16x8*)(Qg + (size_t)(it * 64 + wq0 + c) * KSZ + g * 8);
  s16x8 bq1 = *(const s16x8*)(Qg + (size_t)(it * 64 + wq0 + c) * KSZ + 32 + g * 8);

  // staging source offsets (per thread)
  const u16* kgA0 = Kg + (size_t)sr * KSZ + sc * 8;          // +t*128*KSZ
  const u16* kgA1 = Kg + (size_t)(sr + 32) * KSZ + sc * 8;
  const u16* vgA0 = Vg + (size_t)sr * SS + sc * 8;           // +t*128
  const u16* vgA1 = Vg + (size_t)(sr + 32) * SS + sc * 8;

  // prologue: super-tile 0 (both subs) -> buf0
  u16x8 krA0 = *(const u16x8*)(kgA0);
  u16x8 krA1 = *(const u16x8*)(kgA1);
  u16x8 krB0 = *(const u16x8*)(kgA0 + (size_t)64 * KSZ);
  u16x8 krB1 = *(const u16x8*)(kgA1 + (size_t)64 * KSZ);
  u16x8 vrA0 = *(const u16x8*)(vgA0);
  u16x8 vrA1 = *(const u16x8*)(vgA1);
  u16x8 vrB0 = *(const u16x8*)(vgA0 + 64);
  u16x8 vrB1 = *(const u16x8*)(vgA1 + 64);
  *(u16x8*)&Ks[0][0][soA] = krA0; *(u16x8*)&Ks[0][0][soB] = krA1;
  *(u16x8*)&Ks[0][1][soA] = krB0; *(u16x8*)&Ks[0][1][soB] = krB1;
  *(u16x8*)&Vt[0][0][soA] = vrA0; *(u16x8*)&Vt[0][0][soB] = vrA1;
  *(u16x8*)&Vt[0][1][soA] = vrB0; *(u16x8*)&Vt[0][1][soB] = vrB1;
  if (NT > 1) {
    krA0 = *(const u16x8*)(kgA0 + (size_t)128 * KSZ);
    krA1 = *(const u16x8*)(kgA1 + (size_t)128 * KSZ);
    krB0 = *(const u16x8*)(kgA0 + (size_t)192 * KSZ);
    krB1 = *(const u16x8*)(kgA1 + (size_t)192 * KSZ);
    vrA0 = *(const u16x8*)(vgA0 + 128);
    vrA1 = *(const u16x8*)(vgA1 + 128);
    vrB0 = *(const u16x8*)(vgA0 + 192);
    vrB1 = *(const u16x8*)(vgA1 + 192);
  }
  __syncthreads();

  f32x4 o[4];
  #pragma unroll
  for (int mf = 0; mf < 4; ++mf) o[mf] = {0.f, 0.f, 0.f, 0.f};
  float l_i = 0.f;
  const int cswz = c & 7;
  const int qloc = wq0 + c;

  // one 64-key sub-tile: QK -> (mask) -> exp2/cvt_pk -> PV, all in-register P
  auto do_sub = [&](const u16* Kl, const u16* Vl, bool diag) {
    f32x4 s[4];
    #pragma unroll
    for (int mf = 0; mf < 4; ++mf) s[mf] = {0.f, 0.f, 0.f, 0.f};
    __builtin_amdgcn_s_setprio(1);
    #pragma unroll
    for (int ks = 0; ks < 2; ++ks) {
      const s16x8 bq = ks ? bq1 : bq0;
      #pragma unroll
      for (int mf = 0; mf < 4; ++mf) {
        s16x8 ak = *(const s16x8*)&Kl[(mf * 16 + c) * 64 +
                                      (((ks * 4 + g) ^ cswz) * 8)];
        s[mf] = __builtin_amdgcn_mfma_f32_16x16x32_bf16(ak, bq, s[mf], 0, 0, 0);
      }
    }
    __builtin_amdgcn_s_setprio(0);
    if (diag) {
      #pragma unroll
      for (int mf = 0; mf < 4; ++mf)
        #pragma unroll
        for (int r = 0; r < 4; ++r)
          if (mf * 16 + g * 4 + r > qloc) s[mf][r] = -1e30f;
    }
    s16x4 bp[4];
    #pragma unroll
    for (int mf = 0; mf < 4; ++mf) {
      float p0 = __builtin_amdgcn_exp2f(s[mf][0]);
      float p1 = __builtin_amdgcn_exp2f(s[mf][1]);
      float p2 = __builtin_amdgcn_exp2f(s[mf][2]);
      float p3 = __builtin_amdgcn_exp2f(s[mf][3]);
      l_i += (p0 + p1) + (p2 + p3);
      u32x2 pk;
      pk[0] = cvtpk_bf16(p0, p1);
      pk[1] = cvtpk_bf16(p2, p3);
      bp[mf] = __builtin_bit_cast(s16x4, pk);
    }
    __builtin_amdgcn_s_setprio(1);
    #pragma unroll
    for (int mf = 0; mf < 4; ++mf) {
      #pragma unroll
      for (int kb = 0; kb < 4; ++kb) {
        s16x4 av = *(const s16x4*)&Vl[(mf * 16 + c) * 64 +
                                      (((kb * 2 + (g >> 1)) ^ cswz) * 8) +
                                      (g & 1) * 4];
        o[mf] = mfma16(av, bp[kb], o[mf]);
      }
    }
    __builtin_amdgcn_s_setprio(0);
  };

  #pragma unroll 1
  for (int t = 0; t < NT; ++t) {
    const int buf = t & 1;
    if (t + 1 < NT) {
      const int nb = buf ^ 1;
      *(u16x8*)&Ks[nb][0][soA] = krA0; *(u16x8*)&Ks[nb][0][soB] = krA1;
      *(u16x8*)&Ks[nb][1][soA] = krB0; *(u16x8*)&Ks[nb][1][soB] = krB1;
      *(u16x8*)&Vt[nb][0][soA] = vrA0; *(u16x8*)&Vt[nb][0][soB] = vrA1;
      *(u16x8*)&Vt[nb][1][soA] = vrB0; *(u16x8*)&Vt[nb][1][soB] = vrB1;
      if (t + 2 < NT) {
        const size_t k2 = (size_t)(t + 2) * 128;
        krA0 = *(const u16x8*)(kgA0 + k2 * KSZ);
        krA1 = *(const u16x8*)(kgA1 + k2 * KSZ);
        krB0 = *(const u16x8*)(kgA0 + (k2 + 64) * KSZ);
        krB1 = *(const u16x8*)(kgA1 + (k2 + 64) * KSZ);
        vrA0 = *(const u16x8*)(vgA0 + k2);
        vrA1 = *(const u16x8*)(vgA1 + k2);
        vrB0 = *(const u16x8*)(vgA0 + k2 + 64);
        vrB1 = *(const u16x8*)(vgA1 + k2 + 64);
      }
    }
    // sub 0 (always valid: 2t <= it by construction of NT)
    do_sub(&Ks[buf][0][0], &Vt[buf][0][0], (2 * t) == it);
    // sub 1 (skip past the diagonal; wave-uniform branch)
    if (2 * t + 1 <= it)
      do_sub(&Ks[buf][1][0], &Vt[buf][1][0], (2 * t + 1) == it);
    __syncthreads();
  }
  l_i += __shfl_xor(l_i, 16);
  l_i += __shfl_xor(l_i, 32);
  const float inv = 1.0f / l_i;
  const int q = it * 64 + wq0 + c;
  #pragma unroll
  for (int mf = 0; mf < 4; ++mf) {
    u16x4 hv;
    #pragma unroll
    for (int r = 0; r < 4; ++r) hv[r] = bf16rne(o[mf][r] * inv);
    *(u16x4*)(headsB + plane + (size_t)q * KSZ + mf * 16 + g * 4) = hv;
  }
}

// ---------------------------------------------------------------------------
// Out: out[m][n] = sum_k' heads'[m][k'] * BpT[n][k'],  M=4096 N=64 K=1024.
// ---------------------------------------------------------------------------
__global__ __launch_bounds__(256) void out_kernel(
    const u16* __restrict__ headsB, const u16* __restrict__ BpT,
    float* __restrict__ out) {
  const int m0 = blockIdx.x * 16;
  const int tid = threadIdx.x;
  const int wave = tid >> 6, lane = tid & 63;
  const int g = lane >> 4, c = lane & 15;

  const int m = m0 + c;
  const int b = m >> 11, s = m & 2047;

  f32x4 acc[4];
  #pragma unroll
  for (int nf = 0; nf < 4; ++nf) acc[nf] = {0.f, 0.f, 0.f, 0.f};

  #pragma unroll
  for (int it = 0; it < 8; ++it) {
    const int kb = wave * 256 + it * 32;
    const int hh = kb >> 6, kk = (kb & 63) + g * 8;
    s16x8 a = *(const s16x8*)(headsB +
        ((size_t)(b * HH + hh) * SS + s) * KSZ + kk);
    #pragma unroll
    for (int nf = 0; nf < 4; ++nf) {
      s16x8 bf = *(const s16x8*)(BpT +
          (size_t)(nf * 16 + c) * (HH * KSZ) + kb + g * 8);
      acc[nf] = __builtin_amdgcn_mfma_f32_16x16x32_bf16(a, bf, acc[nf], 0, 0, 0);
    }
  }

  __shared__ __align__(16) float red[4][64][16];
  #pragma unroll
  for (int nf = 0; nf < 4; ++nf)
    *(f32x4*)&red[wave][lane][nf * 4] = acc[nf];
  __syncthreads();

  const int mi = tid >> 4, n4 = (tid & 15) * 4;
  const int gg = mi >> 2, rr = mi & 3;
  float4 res;
  float* rp = &res.x;
  #pragma unroll
  for (int j = 0; j < 4; ++j) {
    int n = n4 + j;
    int cc = n & 15, nf = n >> 4;
    rp[j] = red[0][gg * 16 + cc][nf * 4 + rr] + red[1][gg * 16 + cc][nf * 4 + rr] +
            red[2][gg * 16 + cc][nf * 4 + rr] + red[3][gg * 16 + cc][nf * 4 + rr];
  }
  *(float4*)(out + (size_t)(m0 + mi) * KSZ + n4) = res;
}

extern "C" void kernel_launch(void* const* d_in, const int* in_sizes, int n_in,
                              void* d_out, int out_size, void* d_ws, size_t ws_size,
                              hipStream_t stream) {
  const float* x    = (const float*)d_in[0];
  const float* Wq   = (const float*)d_in[1];
  const float* Wk   = (const float*)d_in[2];
  const float* Wv   = (const float*)d_in[3];
  const float* kern = (const float*)d_in[4];
  float* out = (float*)d_out;

  u16* xb     = (u16*)d_ws;                          // 8.4 MB
  u16* Wt     = xb + (size_t)4096 * 1024;            // 6.3 MB
  u16* qkvT   = Wt + (size_t)3 * 1024 * 1024;        // 25.2 MB
  u16* headsB = qkvT + (size_t)3 * BB * HH * SS * KSZ;  // 8.4 MB
  u16* BpT    = headsB + (size_t)BB * HH * SS * KSZ;    // 0.13 MB

  prep_all<<<dim3(2880), 256, 0, stream>>>(x, Wq, Wk, Wv, kern, xb, Wt, BpT);
  proj_kernel<<<dim3(768), 256, 0, stream>>>(xb, Wt, qkvT);
  attn_kernel<<<dim3(1024), 256, 0, stream>>>(qkvT, headsB);
  out_kernel<<<dim3(256), 256, 0, stream>>>(headsB, BpT, out);
}

// Round 9
// 159.555 us; speedup vs baseline: 1.0224x; 1.0224x over previous
//
#include <hip/hip_runtime.h>
#include <hip/hip_bf16.h>

#define BB 2
#define SS 2048
#define DD 1024
#define HH 16
#define KSZ 64

typedef __attribute__((ext_vector_type(8))) short s16x8;   // MFMA A/B frag (8 bf16)
typedef __attribute__((ext_vector_type(4))) short s16x4;   // K=16 MFMA frag (4 bf16)
typedef __attribute__((ext_vector_type(4))) float f32x4;   // MFMA C/D frag
typedef __attribute__((ext_vector_type(8))) unsigned short u16x8;
typedef __attribute__((ext_vector_type(4))) unsigned short u16x4;
typedef __attribute__((ext_vector_type(2))) unsigned int u32x2;
typedef unsigned short u16;

__device__ __forceinline__ u16 bf16rne(float f) {
  unsigned int u = __float_as_uint(f);
  unsigned int r = (u + 0x7FFFu + ((u >> 16) & 1u)) >> 16;
  return (u16)r;
}

// packed f32x2 -> bf16x2 (RNE), no builtin on gfx950 (T12 recipe)
__device__ __forceinline__ unsigned int cvtpk_bf16(float lo, float hi) {
  unsigned int r;
  asm("v_cvt_pk_bf16_f32 %0, %1, %2" : "=v"(r) : "v"(lo), "v"(hi));
  return r;
}

// 16x16x16 bf16 MFMA (K=16): builtin name varies across ROCm; hedge.
#if __has_builtin(__builtin_amdgcn_mfma_f32_16x16x16_bf16)
__device__ __forceinline__ f32x4 mfma16(s16x4 a, s16x4 b, f32x4 c) {
  return __builtin_amdgcn_mfma_f32_16x16x16_bf16(a, b, c, 0, 0, 0);
}
#elif __has_builtin(__builtin_amdgcn_mfma_f32_16x16x16bf16_1k)
__device__ __forceinline__ f32x4 mfma16(s16x4 a, s16x4 b, f32x4 c) {
  return __builtin_amdgcn_mfma_f32_16x16x16bf16_1k(a, b, c, 0, 0, 0);
}
#else
__device__ __forceinline__ f32x4 mfma16(s16x4 a, s16x4 b, f32x4 c) {
  asm("s_nop 1\n\tv_mfma_f32_16x16x16_bf16 %0, %1, %2, %0"
      : "+v"(c) : "v"(a), "v"(b));
  return c;
}
#endif

__device__ __forceinline__ void lds_dma16(const u16* g, u16* l) {
  __builtin_amdgcn_global_load_lds(
      (const __attribute__((address_space(1))) unsigned int*)(const void*)g,
      (__attribute__((address_space(3))) unsigned int*)(void*)l, 16, 0, 0);
}

// ---------------------------------------------------------------------------
// Merged prep (flat grid 2880): [0,2048) cast x->bf16; [2048,2816) transpose
// W->Wt[n][d]; [2816,2880) out-weight permute.
// ---------------------------------------------------------------------------
__global__ __launch_bounds__(256) void prep_all(
    const float* __restrict__ x, const float* __restrict__ Wq,
    const float* __restrict__ Wk, const float* __restrict__ Wv,
    const float* __restrict__ kern, u16* __restrict__ xb,
    u16* __restrict__ Wt, u16* __restrict__ BpT) {
  __shared__ float Ts[64][65];
  const int bid = blockIdx.x;
  const int tid = threadIdx.x;
  if (bid < 2048) {
    int idx = (bid * 256 + tid) * 8;
    float4 a = *(const float4*)(x + idx);
    float4 b = *(const float4*)(x + idx + 4);
    u16x8 v;
    v[0] = bf16rne(a.x); v[1] = bf16rne(a.y); v[2] = bf16rne(a.z); v[3] = bf16rne(a.w);
    v[4] = bf16rne(b.x); v[5] = bf16rne(b.y); v[6] = bf16rne(b.z); v[7] = bf16rne(b.w);
    *(u16x8*)(xb + idx) = v;
  } else if (bid < 2816) {
    const int bx = bid - 2048;
    const int p = bx >> 8, rem = bx & 255;
    const int d0 = (rem & 15) * 64, n0 = (rem >> 4) * 64;
    const float* W = (p == 0) ? Wq : (p == 1) ? Wk : Wv;
    u16* Wo = Wt + (size_t)p * DD * DD;
    #pragma unroll
    for (int i = 0; i < 4; ++i) {
      int f4 = tid + i * 256;
      int r = f4 >> 4, c4 = f4 & 15;
      float4 v = *(const float4*)(W + (size_t)(d0 + r) * DD + n0 + c4 * 4);
      Ts[r][c4 * 4 + 0] = v.x; Ts[r][c4 * 4 + 1] = v.y;
      Ts[r][c4 * 4 + 2] = v.z; Ts[r][c4 * 4 + 3] = v.w;
    }
    __syncthreads();
    #pragma unroll
    for (int i = 0; i < 4; ++i) {
      int ch = tid + i * 256;
      int n = ch >> 4, d4 = ch & 15;
      u16x4 o;
      #pragma unroll
      for (int j = 0; j < 4; ++j) o[j] = bf16rne(Ts[d4 * 4 + j][n]);
      *(u16x4*)(Wo + (size_t)(n0 + n) * DD + d0 + d4 * 4) = o;
    }
  } else {
    const int n = bid - 2816;
    const int k4 = tid * 4;
    u16x4 o;
    #pragma unroll
    for (int j = 0; j < 4; ++j) {
      int kp = k4 + j;
      int h = kp >> 6, k = kp & 63;
      o[j] = bf16rne(kern[(size_t)(k * HH + h) * KSZ + n]);
    }
    *(u16x4*)(BpT + (size_t)n * (HH * KSZ) + k4) = o;
  }
}

// ---------------------------------------------------------------------------
// Proj v7: 128x128 tile, 512 THREADS (8 waves, 2M x 4N, 64x32 out/wave).
// Same grid 768 and same 384 MB staging traffic as v5, but 24 waves/CU
// (was 12). R3 evidence: per-byte efficiency improves with waves (57us at
// 1.5x traffic/24 waves vs 45us at 1x/12) -> latency-bound; this adds
// latency-hiding contexts at constant traffic. v5's 3-buffer counted-vmcnt
// loop kept; per-wave DMA = 2/tile -> vmcnt(2) drains exactly tile t.
// __launch_bounds__(512,6) -> 3 blocks/CU (144KB LDS), VGPR <= 85.
// ---------------------------------------------------------------------------
__global__ __launch_bounds__(512, 6) void proj_kernel(
    const u16* __restrict__ xb, const u16* __restrict__ Wt,
    u16* __restrict__ qkvT) {
  const int xcd = blockIdx.x & 7;
  const int idx = blockIdx.x >> 3;                 // 0..95
  const int mt = (xcd >> 1) * 8 + (idx & 7);
  const int nt = (xcd & 1) * 4 + ((idx >> 3) & 3);
  const int p  = idx >> 5;                         // 0..2
  const int m0 = mt * 128, n0 = nt * 128;
  const u16* W = Wt + (size_t)p * DD * DD;         // [n][d]
  u16* outp = qkvT + (size_t)p * (BB * HH * SS * KSZ);

  // 3 staging buffers of 16 KB each (A[128][32] 8KB + B[128][32] 8KB).
  __shared__ __align__(16) unsigned char raw[49152];
  u16* lds = (u16*)raw;
  u16* Cs  = (u16*)raw;            // [128][136] epilogue reuse (34.8 KB)

  const int tid = threadIdx.x;
  const int wave = tid >> 6, lane = tid & 63;      // wave 0..7
  const int g = lane >> 4, c = lane & 15;
  const int mbase = (wave & 1) * 64, nbase = (wave >> 1) * 32;

  const int lr = lane >> 2, lc = lane & 3;
  const int swz = (lc ^ ((lr >> 1) & 3)) * 8;      // elems
  const int rS = wave * 16;                        // one 16-row slab per wave
  const u16* srcA = xb + (size_t)(m0 + rS + lr) * DD + swz;
  const u16* srcB = W  + (size_t)(n0 + rS + lr) * DD + swz;
  const int sl = rS * 32;                          // LDS slab offset (u16)

  f32x4 acc[4][2];
  #pragma unroll
  for (int i = 0; i < 4; ++i)
    #pragma unroll
    for (int j = 0; j < 2; ++j) acc[i][j] = {0.f, 0.f, 0.f, 0.f};

  // prologue: tile 0 -> buf0, tile 1 -> buf1 (4 DMAs/wave in flight)
  {
    u16* A0 = lds;                u16* B0 = lds + 4096;
    u16* A1 = lds + 8192;         u16* B1 = lds + 8192 + 4096;
    lds_dma16(srcA, A0 + sl);       lds_dma16(srcB, B0 + sl);
    lds_dma16(srcA + 32, A1 + sl);  lds_dma16(srcB + 32, B1 + sl);
  }

  const int jsw = (c >> 1) & 3;                    // frag-read swizzle term
  int cr = 0;                                      // t % 3
  #pragma unroll 1
  for (int t = 0; t < 31; ++t) {
    asm volatile("s_waitcnt vmcnt(2)" ::: "memory");   // drain tile t only
    __builtin_amdgcn_s_barrier();
    __builtin_amdgcn_sched_barrier(0);
    if (t <= 29) {
      const int st = cr ? cr - 1 : 2;              // (t+2) % 3
      const int ko = (t + 2) * 32;
      u16* An = lds + st * 8192;
      u16* Bn = An + 4096;
      lds_dma16(srcA + ko, An + sl);  lds_dma16(srcB + ko, Bn + sl);
    }
    u16* Ac = lds + cr * 8192;
    u16* Bc = Ac + 4096;
    s16x8 af[4], bfr[2];
    #pragma unroll
    for (int mf = 0; mf < 4; ++mf)
      af[mf] = *(const s16x8*)&Ac[(mbase + mf * 16 + c) * 32 + ((g ^ jsw) * 8)];
    #pragma unroll
    for (int nf = 0; nf < 2; ++nf)
      bfr[nf] = *(const s16x8*)&Bc[(nbase + nf * 16 + c) * 32 + ((g ^ jsw) * 8)];
    #pragma unroll
    for (int mf = 0; mf < 4; ++mf)
      #pragma unroll
      for (int nf = 0; nf < 2; ++nf)
        acc[mf][nf] = __builtin_amdgcn_mfma_f32_16x16x32_bf16(
            af[mf], bfr[nf], acc[mf][nf], 0, 0, 0);
    cr = (cr >= 2) ? 0 : cr + 1;
  }
  asm volatile("s_waitcnt vmcnt(0)" ::: "memory");
  __builtin_amdgcn_s_barrier();
  __builtin_amdgcn_sched_barrier(0);
  {
    u16* Ac = lds + cr * 8192;
    u16* Bc = Ac + 4096;
    s16x8 af[4], bfr[2];
    #pragma unroll
    for (int mf = 0; mf < 4; ++mf)
      af[mf] = *(const s16x8*)&Ac[(mbase + mf * 16 + c) * 32 + ((g ^ jsw) * 8)];
    #pragma unroll
    for (int nf = 0; nf < 2; ++nf)
      bfr[nf] = *(const s16x8*)&Bc[(nbase + nf * 16 + c) * 32 + ((g ^ jsw) * 8)];
    #pragma unroll
    for (int mf = 0; mf < 4; ++mf)
      #pragma unroll
      for (int nf = 0; nf < 2; ++nf)
        acc[mf][nf] = __builtin_amdgcn_mfma_f32_16x16x32_bf16(
            af[mf], bfr[nf], acc[mf][nf], 0, 0, 0);
  }
  __syncthreads();   // all frag reads done before Cs alias reuse

  const float cscale = (p == 0) ? 0.125f * 1.44269504f : 1.0f;
  #pragma unroll
  for (int mf = 0; mf < 4; ++mf)
    #pragma unroll
    for (int nf = 0; nf < 2; ++nf)
      #pragma unroll
      for (int r = 0; r < 4; ++r)
        Cs[(mbase + mf * 16 + g * 4 + r) * 136 + nbase + nf * 16 + c] =
            bf16rne(acc[mf][nf][r] * cscale);
  __syncthreads();
  const int b = m0 >> 11;
  if (p < 2) {
    int hh = tid >> 5, s5 = tid & 31;
    #pragma unroll
    for (int i = 0; i < 4; ++i) {
      int row = i * 32 + s5;
      int s = (m0 + row) & 2047;
      u16x8 v;
      #pragma unroll
      for (int kp = 0; kp < 8; ++kp) v[kp] = Cs[row * 136 + kp * 16 + hh];
      *(u16x8*)(outp + ((size_t)(b * HH + hh) * SS + s) * KSZ + (n0 >> 4)) = v;
    }
  } else {
    const int s0 = m0 & 2047;
    #pragma unroll
    for (int i = 0; i < 4; ++i) {
      int chunk = tid + i * 512;
      int colid = chunk >> 4;
      int hh = colid >> 3, kp = colid & 7;
      int s8 = chunk & 15;
      u16x8 v;
      #pragma unroll
      for (int j = 0; j < 8; ++j) v[j] = Cs[(s8 * 8 + j) * 136 + kp * 16 + hh];
      *(u16x8*)(outp + ((size_t)(b * HH + hh) * KSZ + (n0 >> 4) + kp) * SS +
                s0 + s8 * 8) = v;
    }
  }
}

// ---------------------------------------------------------------------------
// Attention v10 (R7-verified best, ~40us): IN-REGISTER P. QK output
// s[mf][r] = P^T[key=mf*16+g*4+r][q=c] is exactly the B-fragment layout of
// mfma_f32_16x16x16_bf16 -> PV uses four K=16 MFMAs, bp = cvt_pk(s).
// Zero Ps LDS. 32KB LDS, 1024 blocks, 4/CU. (R8: KVBLK=128 variant
// regressed -- 2 blocks/CU + 2x bank conflicts; reverted.)
// ---------------------------------------------------------------------------
__global__ __launch_bounds__(256, 4) void attn_kernel(
    const u16* __restrict__ qkvT, u16* __restrict__ headsB) {
  const int bid = blockIdx.x;
  const int hb = bid & 31;
  const int u  = bid >> 5;                               // 0..31
  const int x  = u & 7, w = u >> 3;
  const int it = (w == 0) ? x : (w == 1) ? 15 - x : (w == 2) ? 16 + x : 31 - x;
  const int h = hb & 15, b = hb >> 4;
  const size_t plane = (size_t)(b * HH + h) * SS * KSZ;
  const size_t PSZ = (size_t)BB * HH * SS * KSZ;
  const u16* Qg = qkvT + plane;            // [s][k], pre-scaled 0.125*log2e
  const u16* Kg = qkvT + PSZ + plane;      // [s][k]
  const u16* Vg = qkvT + 2 * PSZ + plane;  // [k][s]

  __shared__ u16 Ks[2][64 * 64];   // [key][d], XOR chunk swizzle
  __shared__ u16 Vt[2][64 * 64];   // [d][key], XOR chunk swizzle

  const int tid = threadIdx.x;
  const int lane = tid & 63;
  const int g = lane >> 4, c = lane & 15;
  const int wq0 = (tid >> 6) * 16;
  const int sr = tid >> 3, sc = tid & 7;
  const int soA = sr * 64 + ((sc ^ (sr & 7)) * 8);   // (sr+32)&7 == sr&7
  const int soB = soA + 32 * 64;

  // Q fragments: loop-invariant, straight from global (one 2KB region/wave)
  s16x8 bq0 = *(const s16x8*)(Qg + (size_t)(it * 64 + wq0 + c) * KSZ + g * 8);
  s16x8 bq1 = *(const s16x8*)(Qg + (size_t)(it * 64 + wq0 + c) * KSZ + 32 + g * 8);

  // prologue: tile 0 -> LDS buf0; prefetch tile 1 into regs
  u16x8 kr0 = *(const u16x8*)(Kg + (size_t)sr * KSZ + sc * 8);
  u16x8 kr1 = *(const u16x8*)(Kg + (size_t)(sr + 32) * KSZ + sc * 8);
  u16x8 vr0 = *(const u16x8*)(Vg + (size_t)sr * SS + sc * 8);
  u16x8 vr1 = *(const u16x8*)(Vg + (size_t)(sr + 32) * SS + sc * 8);
  *(u16x8*)&Ks[0][soA] = kr0; *(u16x8*)&Ks[0][soB] = kr1;
  *(u16x8*)&Vt[0][soA] = vr0; *(u16x8*)&Vt[0][soB] = vr1;
  kr0 = *(const u16x8*)(Kg + (size_t)(64 + sr) * KSZ + sc * 8);
  kr1 = *(const u16x8*)(Kg + (size_t)(64 + sr + 32) * KSZ + sc * 8);
  vr0 = *(const u16x8*)(Vg + (size_t)sr * SS + 64 + sc * 8);
  vr1 = *(const u16x8*)(Vg + (size_t)(sr + 32) * SS + 64 + sc * 8);
  __syncthreads();

  f32x4 o[4];
  #pragma unroll
  for (int mf = 0; mf < 4; ++mf) o[mf] = {0.f, 0.f, 0.f, 0.f};
  float l_i = 0.f;
  const int cswz = c & 7;
  const int qloc = wq0 + c;

  #pragma unroll 1
  for (int t = 0; t <= it; ++t) {
    const int buf = t & 1;
    if (t < it) {
      const int nb = buf ^ 1;
      *(u16x8*)&Ks[nb][soA] = kr0; *(u16x8*)&Ks[nb][soB] = kr1;
      *(u16x8*)&Vt[nb][soA] = vr0; *(u16x8*)&Vt[nb][soB] = vr1;
      if (t + 2 <= it) {
        const int kv2 = t + 2;
        kr0 = *(const u16x8*)(Kg + (size_t)(kv2 * 64 + sr) * KSZ + sc * 8);
        kr1 = *(const u16x8*)(Kg + (size_t)(kv2 * 64 + sr + 32) * KSZ + sc * 8);
        vr0 = *(const u16x8*)(Vg + (size_t)sr * SS + kv2 * 64 + sc * 8);
        vr1 = *(const u16x8*)(Vg + (size_t)(sr + 32) * SS + kv2 * 64 + sc * 8);
      }
    }
    // S^T = K . Q^T  (K=32 MFMAs, LDS K reads, 2-way banks)
    f32x4 s[4];
    #pragma unroll
    for (int mf = 0; mf < 4; ++mf) s[mf] = {0.f, 0.f, 0.f, 0.f};
    __builtin_amdgcn_s_setprio(1);
    #pragma unroll
    for (int ks = 0; ks < 2; ++ks) {
      const s16x8 bq = ks ? bq1 : bq0;
      #pragma unroll
      for (int mf = 0; mf < 4; ++mf) {
        s16x8 ak = *(const s16x8*)&Ks[buf][(mf * 16 + c) * 64 +
                                          (((ks * 4 + g) ^ cswz) * 8)];
        s[mf] = __builtin_amdgcn_mfma_f32_16x16x32_bf16(ak, bq, s[mf], 0, 0, 0);
      }
    }
    __builtin_amdgcn_s_setprio(0);
    // causal mask on diagonal tile
    if (t == it) {
      #pragma unroll
      for (int mf = 0; mf < 4; ++mf)
        #pragma unroll
        for (int r = 0; r < 4; ++r)
          if (mf * 16 + g * 4 + r > qloc) s[mf][r] = -1e30f;
    }
    // p = exp2(s'); accumulate l; pack P IN REGISTERS (bp[kb] = s[kb] bf16)
    s16x4 bp[4];
    #pragma unroll
    for (int mf = 0; mf < 4; ++mf) {
      float p0 = __builtin_amdgcn_exp2f(s[mf][0]);
      float p1 = __builtin_amdgcn_exp2f(s[mf][1]);
      float p2 = __builtin_amdgcn_exp2f(s[mf][2]);
      float p3 = __builtin_amdgcn_exp2f(s[mf][3]);
      l_i += (p0 + p1) + (p2 + p3);
      u32x2 pk;
      pk[0] = cvtpk_bf16(p0, p1);
      pk[1] = cvtpk_bf16(p2, p3);
      bp[mf] = __builtin_bit_cast(s16x4, pk);
    }
    // O^T += V^T . P^T  via four K=16 MFMAs per frag: A = V^T[d=mf*16+c]
    // [k=kb*16+g*4+i] (b64 LDS reads), B = bp[kb] (in-register).
    __builtin_amdgcn_s_setprio(1);
    #pragma unroll
    for (int mf = 0; mf < 4; ++mf) {
      #pragma unroll
      for (int kb = 0; kb < 4; ++kb) {
        s16x4 av = *(const s16x4*)&Vt[buf][(mf * 16 + c) * 64 +
                                           (((kb * 2 + (g >> 1)) ^ cswz) * 8) +
                                           (g & 1) * 4];
        o[mf] = mfma16(av, bp[kb], o[mf]);
      }
    }
    __builtin_amdgcn_s_setprio(0);
    __syncthreads();
  }
  l_i += __shfl_xor(l_i, 16);
  l_i += __shfl_xor(l_i, 32);
  const float inv = 1.0f / l_i;
  const int q = it * 64 + wq0 + c;
  #pragma unroll
  for (int mf = 0; mf < 4; ++mf) {
    u16x4 hv;
    #pragma unroll
    for (int r = 0; r < 4; ++r) hv[r] = bf16rne(o[mf][r] * inv);
    *(u16x4*)(headsB + plane + (size_t)q * KSZ + mf * 16 + g * 4) = hv;
  }
}

// ---------------------------------------------------------------------------
// Out: out[m][n] = sum_k' heads'[m][k'] * BpT[n][k'],  M=4096 N=64 K=1024.
// ---------------------------------------------------------------------------
__global__ __launch_bounds__(256) void out_kernel(
    const u16* __restrict__ headsB, const u16* __restrict__ BpT,
    float* __restrict__ out) {
  const int m0 = blockIdx.x * 16;
  const int tid = threadIdx.x;
  const int wave = tid >> 6, lane = tid & 63;
  const int g = lane >> 4, c = lane & 15;

  const int m = m0 + c;
  const int b = m >> 11, s = m & 2047;

  f32x4 acc[4];
  #pragma unroll
  for (int nf = 0; nf < 4; ++nf) acc[nf] = {0.f, 0.f, 0.f, 0.f};

  #pragma unroll
  for (int it = 0; it < 8; ++it) {
    const int kb = wave * 256 + it * 32;
    const int hh = kb >> 6, kk = (kb & 63) + g * 8;
    s16x8 a = *(const s16x8*)(headsB +
        ((size_t)(b * HH + hh) * SS + s) * KSZ + kk);
    #pragma unroll
    for (int nf = 0; nf < 4; ++nf) {
      s16x8 bf = *(const s16x8*)(BpT +
          (size_t)(nf * 16 + c) * (HH * KSZ) + kb + g * 8);
      acc[nf] = __builtin_amdgcn_mfma_f32_16x16x32_bf16(a, bf, acc[nf], 0, 0, 0);
    }
  }

  __shared__ __align__(16) float red[4][64][16];
  #pragma unroll
  for (int nf = 0; nf < 4; ++nf)
    *(f32x4*)&red[wave][lane][nf * 4] = acc[nf];
  __syncthreads();

  const int mi = tid >> 4, n4 = (tid & 15) * 4;
  const int gg = mi >> 2, rr = mi & 3;
  float4 res;
  float* rp = &res.x;
  #pragma unroll
  for (int j = 0; j < 4; ++j) {
    int n = n4 + j;
    int cc = n & 15, nf = n >> 4;
    rp[j] = red[0][gg * 16 + cc][nf * 4 + rr] + red[1][gg * 16 + cc][nf * 4 + rr] +
            red[2][gg * 16 + cc][nf * 4 + rr] + red[3][gg * 16 + cc][nf * 4 + rr];
  }
  *(float4*)(out + (size_t)(m0 + mi) * KSZ + n4) = res;
}

extern "C" void kernel_launch(void* const* d_in, const int* in_sizes, int n_in,
                              void* d_out, int out_size, void* d_ws, size_t ws_size,
                              hipStream_t stream) {
  const float* x    = (const float*)d_in[0];
  const float* Wq   = (const float*)d_in[1];
  const float* Wk   = (const float*)d_in[2];
  const float* Wv   = (const float*)d_in[3];
  const float* kern = (const float*)d_in[4];
  float* out = (float*)d_out;

  u16* xb     = (u16*)d_ws;                          // 8.4 MB
  u16* Wt     = xb + (size_t)4096 * 1024;            // 6.3 MB
  u16* qkvT   = Wt + (size_t)3 * 1024 * 1024;        // 25.2 MB
  u16* headsB = qkvT + (size_t)3 * BB * HH * SS * KSZ;  // 8.4 MB
  u16* BpT    = headsB + (size_t)BB * HH * SS * KSZ;    // 0.13 MB

  prep_all<<<dim3(2880), 256, 0, stream>>>(x, Wq, Wk, Wv, kern, xb, Wt, BpT);
  proj_kernel<<<dim3(768), 512, 0, stream>>>(xb, Wt, qkvT);
  attn_kernel<<<dim3(1024), 256, 0, stream>>>(qkvT, headsB);
  out_kernel<<<dim3(256), 256, 0, stream>>>(headsB, BpT, out);
}

// Round 10
// 156.794 us; speedup vs baseline: 1.0404x; 1.0176x over previous
//
#include <hip/hip_runtime.h>
#include <hip/hip_bf16.h>

#define BB 2
#define SS 2048
#define DD 1024
#define HH 16
#define KSZ 64

typedef __attribute__((ext_vector_type(8))) short s16x8;   // MFMA A/B frag (8 bf16)
typedef __attribute__((ext_vector_type(4))) short s16x4;   // K=16 MFMA frag (4 bf16)
typedef __attribute__((ext_vector_type(4))) float f32x4;   // MFMA C/D frag
typedef __attribute__((ext_vector_type(8))) unsigned short u16x8;
typedef __attribute__((ext_vector_type(4))) unsigned short u16x4;
typedef __attribute__((ext_vector_type(2))) unsigned int u32x2;
typedef unsigned short u16;

__device__ __forceinline__ u16 bf16rne(float f) {
  unsigned int u = __float_as_uint(f);
  unsigned int r = (u + 0x7FFFu + ((u >> 16) & 1u)) >> 16;
  return (u16)r;
}

// packed f32x2 -> bf16x2 (RNE), no builtin on gfx950 (T12 recipe)
__device__ __forceinline__ unsigned int cvtpk_bf16(float lo, float hi) {
  unsigned int r;
  asm("v_cvt_pk_bf16_f32 %0, %1, %2" : "=v"(r) : "v"(lo), "v"(hi));
  return r;
}

// 16x16x16 bf16 MFMA (K=16): builtin name varies across ROCm; hedge.
#if __has_builtin(__builtin_amdgcn_mfma_f32_16x16x16_bf16)
__device__ __forceinline__ f32x4 mfma16(s16x4 a, s16x4 b, f32x4 c) {
  return __builtin_amdgcn_mfma_f32_16x16x16_bf16(a, b, c, 0, 0, 0);
}
#elif __has_builtin(__builtin_amdgcn_mfma_f32_16x16x16bf16_1k)
__device__ __forceinline__ f32x4 mfma16(s16x4 a, s16x4 b, f32x4 c) {
  return __builtin_amdgcn_mfma_f32_16x16x16bf16_1k(a, b, c, 0, 0, 0);
}
#else
__device__ __forceinline__ f32x4 mfma16(s16x4 a, s16x4 b, f32x4 c) {
  asm("s_nop 1\n\tv_mfma_f32_16x16x16_bf16 %0, %1, %2, %0"
      : "+v"(c) : "v"(a), "v"(b));
  return c;
}
#endif

__device__ __forceinline__ void lds_dma16(const u16* g, u16* l) {
  __builtin_amdgcn_global_load_lds(
      (const __attribute__((address_space(1))) unsigned int*)(const void*)g,
      (__attribute__((address_space(3))) unsigned int*)(void*)l, 16, 0, 0);
}

// ---------------------------------------------------------------------------
// Merged prep (flat grid 2880): [0,2048) cast x->bf16; [2048,2816) transpose
// W->Wt[n][d]; [2816,2880) out-weight permute.
// ---------------------------------------------------------------------------
__global__ __launch_bounds__(256) void prep_all(
    const float* __restrict__ x, const float* __restrict__ Wq,
    const float* __restrict__ Wk, const float* __restrict__ Wv,
    const float* __restrict__ kern, u16* __restrict__ xb,
    u16* __restrict__ Wt, u16* __restrict__ BpT) {
  __shared__ float Ts[64][65];
  const int bid = blockIdx.x;
  const int tid = threadIdx.x;
  if (bid < 2048) {
    int idx = (bid * 256 + tid) * 8;
    float4 a = *(const float4*)(x + idx);
    float4 b = *(const float4*)(x + idx + 4);
    u16x8 v;
    v[0] = bf16rne(a.x); v[1] = bf16rne(a.y); v[2] = bf16rne(a.z); v[3] = bf16rne(a.w);
    v[4] = bf16rne(b.x); v[5] = bf16rne(b.y); v[6] = bf16rne(b.z); v[7] = bf16rne(b.w);
    *(u16x8*)(xb + idx) = v;
  } else if (bid < 2816) {
    const int bx = bid - 2048;
    const int p = bx >> 8, rem = bx & 255;
    const int d0 = (rem & 15) * 64, n0 = (rem >> 4) * 64;
    const float* W = (p == 0) ? Wq : (p == 1) ? Wk : Wv;
    u16* Wo = Wt + (size_t)p * DD * DD;
    #pragma unroll
    for (int i = 0; i < 4; ++i) {
      int f4 = tid + i * 256;
      int r = f4 >> 4, c4 = f4 & 15;
      float4 v = *(const float4*)(W + (size_t)(d0 + r) * DD + n0 + c4 * 4);
      Ts[r][c4 * 4 + 0] = v.x; Ts[r][c4 * 4 + 1] = v.y;
      Ts[r][c4 * 4 + 2] = v.z; Ts[r][c4 * 4 + 3] = v.w;
    }
    __syncthreads();
    #pragma unroll
    for (int i = 0; i < 4; ++i) {
      int ch = tid + i * 256;
      int n = ch >> 4, d4 = ch & 15;
      u16x4 o;
      #pragma unroll
      for (int j = 0; j < 4; ++j) o[j] = bf16rne(Ts[d4 * 4 + j][n]);
      *(u16x4*)(Wo + (size_t)(n0 + n) * DD + d0 + d4 * 4) = o;
    }
  } else {
    const int n = bid - 2816;
    const int k4 = tid * 4;
    u16x4 o;
    #pragma unroll
    for (int j = 0; j < 4; ++j) {
      int kp = k4 + j;
      int h = kp >> 6, k = kp & 63;
      o[j] = bf16rne(kern[(size_t)(k * HH + h) * KSZ + n]);
    }
    *(u16x4*)(BpT + (size_t)n * (HH * KSZ) + k4) = o;
  }
}

// ---------------------------------------------------------------------------
// Proj v7 (R9-verified, 43.1us): 128x128 tile, 512 threads (8 waves), grid
// 768, 3-buffer counted-vmcnt pipeline. 24 waves/CU at 384 MB staging.
// ---------------------------------------------------------------------------
__global__ __launch_bounds__(512, 6) void proj_kernel(
    const u16* __restrict__ xb, const u16* __restrict__ Wt,
    u16* __restrict__ qkvT) {
  const int xcd = blockIdx.x & 7;
  const int idx = blockIdx.x >> 3;                 // 0..95
  const int mt = (xcd >> 1) * 8 + (idx & 7);
  const int nt = (xcd & 1) * 4 + ((idx >> 3) & 3);
  const int p  = idx >> 5;                         // 0..2
  const int m0 = mt * 128, n0 = nt * 128;
  const u16* W = Wt + (size_t)p * DD * DD;         // [n][d]
  u16* outp = qkvT + (size_t)p * (BB * HH * SS * KSZ);

  __shared__ __align__(16) unsigned char raw[49152];
  u16* lds = (u16*)raw;
  u16* Cs  = (u16*)raw;            // [128][136] epilogue reuse (34.8 KB)

  const int tid = threadIdx.x;
  const int wave = tid >> 6, lane = tid & 63;      // wave 0..7
  const int g = lane >> 4, c = lane & 15;
  const int mbase = (wave & 1) * 64, nbase = (wave >> 1) * 32;

  const int lr = lane >> 2, lc = lane & 3;
  const int swz = (lc ^ ((lr >> 1) & 3)) * 8;      // elems
  const int rS = wave * 16;                        // one 16-row slab per wave
  const u16* srcA = xb + (size_t)(m0 + rS + lr) * DD + swz;
  const u16* srcB = W  + (size_t)(n0 + rS + lr) * DD + swz;
  const int sl = rS * 32;                          // LDS slab offset (u16)

  f32x4 acc[4][2];
  #pragma unroll
  for (int i = 0; i < 4; ++i)
    #pragma unroll
    for (int j = 0; j < 2; ++j) acc[i][j] = {0.f, 0.f, 0.f, 0.f};

  // prologue: tile 0 -> buf0, tile 1 -> buf1 (4 DMAs/wave in flight)
  {
    u16* A0 = lds;                u16* B0 = lds + 4096;
    u16* A1 = lds + 8192;         u16* B1 = lds + 8192 + 4096;
    lds_dma16(srcA, A0 + sl);       lds_dma16(srcB, B0 + sl);
    lds_dma16(srcA + 32, A1 + sl);  lds_dma16(srcB + 32, B1 + sl);
  }

  const int jsw = (c >> 1) & 3;                    // frag-read swizzle term
  int cr = 0;                                      // t % 3
  #pragma unroll 1
  for (int t = 0; t < 31; ++t) {
    asm volatile("s_waitcnt vmcnt(2)" ::: "memory");   // drain tile t only
    __builtin_amdgcn_s_barrier();
    __builtin_amdgcn_sched_barrier(0);
    if (t <= 29) {
      const int st = cr ? cr - 1 : 2;              // (t+2) % 3
      const int ko = (t + 2) * 32;
      u16* An = lds + st * 8192;
      u16* Bn = An + 4096;
      lds_dma16(srcA + ko, An + sl);  lds_dma16(srcB + ko, Bn + sl);
    }
    u16* Ac = lds + cr * 8192;
    u16* Bc = Ac + 4096;
    s16x8 af[4], bfr[2];
    #pragma unroll
    for (int mf = 0; mf < 4; ++mf)
      af[mf] = *(const s16x8*)&Ac[(mbase + mf * 16 + c) * 32 + ((g ^ jsw) * 8)];
    #pragma unroll
    for (int nf = 0; nf < 2; ++nf)
      bfr[nf] = *(const s16x8*)&Bc[(nbase + nf * 16 + c) * 32 + ((g ^ jsw) * 8)];
    #pragma unroll
    for (int mf = 0; mf < 4; ++mf)
      #pragma unroll
      for (int nf = 0; nf < 2; ++nf)
        acc[mf][nf] = __builtin_amdgcn_mfma_f32_16x16x32_bf16(
            af[mf], bfr[nf], acc[mf][nf], 0, 0, 0);
    cr = (cr >= 2) ? 0 : cr + 1;
  }
  asm volatile("s_waitcnt vmcnt(0)" ::: "memory");
  __builtin_amdgcn_s_barrier();
  __builtin_amdgcn_sched_barrier(0);
  {
    u16* Ac = lds + cr * 8192;
    u16* Bc = Ac + 4096;
    s16x8 af[4], bfr[2];
    #pragma unroll
    for (int mf = 0; mf < 4; ++mf)
      af[mf] = *(const s16x8*)&Ac[(mbase + mf * 16 + c) * 32 + ((g ^ jsw) * 8)];
    #pragma unroll
    for (int nf = 0; nf < 2; ++nf)
      bfr[nf] = *(const s16x8*)&Bc[(nbase + nf * 16 + c) * 32 + ((g ^ jsw) * 8)];
    #pragma unroll
    for (int mf = 0; mf < 4; ++mf)
      #pragma unroll
      for (int nf = 0; nf < 2; ++nf)
        acc[mf][nf] = __builtin_amdgcn_mfma_f32_16x16x32_bf16(
            af[mf], bfr[nf], acc[mf][nf], 0, 0, 0);
  }
  __syncthreads();   // all frag reads done before Cs alias reuse

  const float cscale = (p == 0) ? 0.125f * 1.44269504f : 1.0f;
  #pragma unroll
  for (int mf = 0; mf < 4; ++mf)
    #pragma unroll
    for (int nf = 0; nf < 2; ++nf)
      #pragma unroll
      for (int r = 0; r < 4; ++r)
        Cs[(mbase + mf * 16 + g * 4 + r) * 136 + nbase + nf * 16 + c] =
            bf16rne(acc[mf][nf][r] * cscale);
  __syncthreads();
  const int b = m0 >> 11;
  if (p < 2) {
    int hh = tid >> 5, s5 = tid & 31;
    #pragma unroll
    for (int i = 0; i < 4; ++i) {
      int row = i * 32 + s5;
      int s = (m0 + row) & 2047;
      u16x8 v;
      #pragma unroll
      for (int kp = 0; kp < 8; ++kp) v[kp] = Cs[row * 136 + kp * 16 + hh];
      *(u16x8*)(outp + ((size_t)(b * HH + hh) * SS + s) * KSZ + (n0 >> 4)) = v;
    }
  } else {
    const int s0 = m0 & 2047;
    #pragma unroll
    for (int i = 0; i < 4; ++i) {
      int chunk = tid + i * 512;
      int colid = chunk >> 4;
      int hh = colid >> 3, kp = colid & 7;
      int s8 = chunk & 15;
      u16x8 v;
      #pragma unroll
      for (int j = 0; j < 8; ++j) v[j] = Cs[(s8 * 8 + j) * 136 + kp * 16 + hh];
      *(u16x8*)(outp + ((size_t)(b * HH + hh) * KSZ + (n0 >> 4) + kp) * SS +
                s0 + s8 * 8) = v;
    }
  }
}

// ---------------------------------------------------------------------------
// Attention v12: v10's in-register P x v9's q-subtile amortization.
// QBLK=128 per block: 4 waves x 32 q-rows (2 subtiles of 16). Each ak/av
// LDS read feeds BOTH subtiles -> LDS bytes per q-row 1.25 -> 0.625 KB
// (R9 analysis: v10 is ~84% LDS-pipe busy); block-iterations halve
// (8.7k vs 16.9k) -> half the barriers. In-register P per subtile:
// s[sq][mf][r] = P^T[key][q] == B-frag of mfma 16x16x16 -> bp = cvt_pk(s).
// 512 blocks x 256 thr, LDS 32 KB, 2 blocks/CU resident (attn was flat
// across 8-16 waves/CU, R2-R6). R4 balanced pairing kept (NT pairs sum 34).
// ---------------------------------------------------------------------------
__global__ __launch_bounds__(256, 2) void attn_kernel(
    const u16* __restrict__ qkvT, u16* __restrict__ headsB) {
  const int bid = blockIdx.x;
  const int hb = bid & 31;
  const int q5 = bid >> 5;                               // 0..15
  const int qt = (q5 < 8) ? q5 : 23 - q5;                // pair (j, 15-j)
  const int h = hb & 15, b = hb >> 4;
  const size_t plane = (size_t)(b * HH + h) * SS * KSZ;
  const size_t PSZ = (size_t)BB * HH * SS * KSZ;
  const u16* Qg = qkvT + plane;            // [s][k], pre-scaled 0.125*log2e
  const u16* Kg = qkvT + PSZ + plane;      // [s][k]
  const u16* Vg = qkvT + 2 * PSZ + plane;  // [k][s]

  __shared__ u16 Ks[2][64 * 64];   // [key][d], XOR chunk swizzle
  __shared__ u16 Vt[2][64 * 64];   // [d][key], XOR chunk swizzle

  const int tid = threadIdx.x;
  const int lane = tid & 63;
  const int g = lane >> 4, c = lane & 15;
  const int wq0 = (tid >> 6) * 32;         // 32 q-rows per wave
  const int sr = tid >> 3, sc = tid & 7;
  const int soA = sr * 64 + ((sc ^ (sr & 7)) * 8);   // (sr+32)&7 == sr&7
  const int soB = soA + 32 * 64;

  const int nt = 2 * qt + 2;               // kv tiles (>= 2)

  // Q fragments: 2 subtiles x 2 k-halves, loop-invariant, from global
  s16x8 bq[2][2];
  #pragma unroll
  for (int sq = 0; sq < 2; ++sq) {
    const size_t qrow = (size_t)(qt * 128 + wq0 + sq * 16 + c) * KSZ;
    bq[sq][0] = *(const s16x8*)(Qg + qrow + g * 8);
    bq[sq][1] = *(const s16x8*)(Qg + qrow + 32 + g * 8);
  }

  // prologue: tile 0 -> LDS buf0; prefetch tile 1 into regs (nt >= 2 always)
  u16x8 kr0 = *(const u16x8*)(Kg + (size_t)sr * KSZ + sc * 8);
  u16x8 kr1 = *(const u16x8*)(Kg + (size_t)(sr + 32) * KSZ + sc * 8);
  u16x8 vr0 = *(const u16x8*)(Vg + (size_t)sr * SS + sc * 8);
  u16x8 vr1 = *(const u16x8*)(Vg + (size_t)(sr + 32) * SS + sc * 8);
  *(u16x8*)&Ks[0][soA] = kr0; *(u16x8*)&Ks[0][soB] = kr1;
  *(u16x8*)&Vt[0][soA] = vr0; *(u16x8*)&Vt[0][soB] = vr1;
  kr0 = *(const u16x8*)(Kg + (size_t)(64 + sr) * KSZ + sc * 8);
  kr1 = *(const u16x8*)(Kg + (size_t)(64 + sr + 32) * KSZ + sc * 8);
  vr0 = *(const u16x8*)(Vg + (size_t)sr * SS + 64 + sc * 8);
  vr1 = *(const u16x8*)(Vg + (size_t)(sr + 32) * SS + 64 + sc * 8);
  __syncthreads();

  f32x4 o[2][4];
  #pragma unroll
  for (int sq = 0; sq < 2; ++sq)
    #pragma unroll
    for (int mf = 0; mf < 4; ++mf) o[sq][mf] = {0.f, 0.f, 0.f, 0.f};
  float l_i[2] = {0.f, 0.f};
  const int cswz = c & 7;

  #pragma unroll 1
  for (int t = 0; t < nt; ++t) {
    const int buf = t & 1;
    if (t + 1 < nt) {
      const int nb = buf ^ 1;
      *(u16x8*)&Ks[nb][soA] = kr0; *(u16x8*)&Ks[nb][soB] = kr1;
      *(u16x8*)&Vt[nb][soA] = vr0; *(u16x8*)&Vt[nb][soB] = vr1;
      if (t + 2 < nt) {
        const int kv2 = t + 2;
        kr0 = *(const u16x8*)(Kg + (size_t)(kv2 * 64 + sr) * KSZ + sc * 8);
        kr1 = *(const u16x8*)(Kg + (size_t)(kv2 * 64 + sr + 32) * KSZ + sc * 8);
        vr0 = *(const u16x8*)(Vg + (size_t)sr * SS + kv2 * 64 + sc * 8);
        vr1 = *(const u16x8*)(Vg + (size_t)(sr + 32) * SS + kv2 * 64 + sc * 8);
      }
    }
    // S^T = K . Q^T : each ak read feeds BOTH subtiles
    f32x4 s[2][4];
    #pragma unroll
    for (int sq = 0; sq < 2; ++sq)
      #pragma unroll
      for (int mf = 0; mf < 4; ++mf) s[sq][mf] = {0.f, 0.f, 0.f, 0.f};
    __builtin_amdgcn_s_setprio(1);
    #pragma unroll
    for (int ks = 0; ks < 2; ++ks) {
      #pragma unroll
      for (int mf = 0; mf < 4; ++mf) {
        s16x8 ak = *(const s16x8*)&Ks[buf][(mf * 16 + c) * 64 +
                                          (((ks * 4 + g) ^ cswz) * 8)];
        s[0][mf] = __builtin_amdgcn_mfma_f32_16x16x32_bf16(ak, bq[0][ks],
                                                           s[0][mf], 0, 0, 0);
        s[1][mf] = __builtin_amdgcn_mfma_f32_16x16x32_bf16(ak, bq[1][ks],
                                                           s[1][mf], 0, 0, 0);
      }
    }
    __builtin_amdgcn_s_setprio(0);
    // causal mask on diagonal super-tiles (t = 2qt, 2qt+1)
    if (t >= 2 * qt) {
      const int rel = (t - 2 * qt) * 64;
      #pragma unroll
      for (int sq = 0; sq < 2; ++sq) {
        const int qloc = wq0 + sq * 16 + c;
        #pragma unroll
        for (int mf = 0; mf < 4; ++mf)
          #pragma unroll
          for (int r = 0; r < 4; ++r)
            if (rel + mf * 16 + g * 4 + r > qloc) s[sq][mf][r] = -1e30f;
      }
    }
    // p = exp2(s'); accumulate l; pack P IN REGISTERS per subtile
    s16x4 bp[2][4];
    #pragma unroll
    for (int sq = 0; sq < 2; ++sq) {
      #pragma unroll
      for (int mf = 0; mf < 4; ++mf) {
        float p0 = __builtin_amdgcn_exp2f(s[sq][mf][0]);
        float p1 = __builtin_amdgcn_exp2f(s[sq][mf][1]);
        float p2 = __builtin_amdgcn_exp2f(s[sq][mf][2]);
        float p3 = __builtin_amdgcn_exp2f(s[sq][mf][3]);
        l_i[sq] += (p0 + p1) + (p2 + p3);
        u32x2 pk;
        pk[0] = cvtpk_bf16(p0, p1);
        pk[1] = cvtpk_bf16(p2, p3);
        bp[sq][mf] = __builtin_bit_cast(s16x4, pk);
      }
    }
    // O^T += V^T . P^T : each av read feeds BOTH subtiles (K=16 MFMAs)
    __builtin_amdgcn_s_setprio(1);
    #pragma unroll
    for (int mf = 0; mf < 4; ++mf) {
      #pragma unroll
      for (int kb = 0; kb < 4; ++kb) {
        s16x4 av = *(const s16x4*)&Vt[buf][(mf * 16 + c) * 64 +
                                           (((kb * 2 + (g >> 1)) ^ cswz) * 8) +
                                           (g & 1) * 4];
        o[0][mf] = mfma16(av, bp[0][kb], o[0][mf]);
        o[1][mf] = mfma16(av, bp[1][kb], o[1][mf]);
      }
    }
    __builtin_amdgcn_s_setprio(0);
    __syncthreads();
  }
  #pragma unroll
  for (int sq = 0; sq < 2; ++sq) {
    float l = l_i[sq];
    l += __shfl_xor(l, 16);
    l += __shfl_xor(l, 32);
    const float inv = 1.0f / l;
    const int q = qt * 128 + wq0 + sq * 16 + c;
    #pragma unroll
    for (int mf = 0; mf < 4; ++mf) {
      u16x4 hv;
      #pragma unroll
      for (int r = 0; r < 4; ++r) hv[r] = bf16rne(o[sq][mf][r] * inv);
      *(u16x4*)(headsB + plane + (size_t)q * KSZ + mf * 16 + g * 4) = hv;
    }
  }
}

// ---------------------------------------------------------------------------
// Out: out[m][n] = sum_k' heads'[m][k'] * BpT[n][k'],  M=4096 N=64 K=1024.
// ---------------------------------------------------------------------------
__global__ __launch_bounds__(256) void out_kernel(
    const u16* __restrict__ headsB, const u16* __restrict__ BpT,
    float* __restrict__ out) {
  const int m0 = blockIdx.x * 16;
  const int tid = threadIdx.x;
  const int wave = tid >> 6, lane = tid & 63;
  const int g = lane >> 4, c = lane & 15;

  const int m = m0 + c;
  const int b = m >> 11, s = m & 2047;

  f32x4 acc[4];
  #pragma unroll
  for (int nf = 0; nf < 4; ++nf) acc[nf] = {0.f, 0.f, 0.f, 0.f};

  #pragma unroll
  for (int it = 0; it < 8; ++it) {
    const int kb = wave * 256 + it * 32;
    const int hh = kb >> 6, kk = (kb & 63) + g * 8;
    s16x8 a = *(const s16x8*)(headsB +
        ((size_t)(b * HH + hh) * SS + s) * KSZ + kk);
    #pragma unroll
    for (int nf = 0; nf < 4; ++nf) {
      s16x8 bf = *(const s16x8*)(BpT +
          (size_t)(nf * 16 + c) * (HH * KSZ) + kb + g * 8);
      acc[nf] = __builtin_amdgcn_mfma_f32_16x16x32_bf16(a, bf, acc[nf], 0, 0, 0);
    }
  }

  __shared__ __align__(16) float red[4][64][16];
  #pragma unroll
  for (int nf = 0; nf < 4; ++nf)
    *(f32x4*)&red[wave][lane][nf * 4] = acc[nf];
  __syncthreads();

  const int mi = tid >> 4, n4 = (tid & 15) * 4;
  const int gg = mi >> 2, rr = mi & 3;
  float4 res;
  float* rp = &res.x;
  #pragma unroll
  for (int j = 0; j < 4; ++j) {
    int n = n4 + j;
    int cc = n & 15, nf = n >> 4;
    rp[j] = red[0][gg * 16 + cc][nf * 4 + rr] + red[1][gg * 16 + cc][nf * 4 + rr] +
            red[2][gg * 16 + cc][nf * 4 + rr] + red[3][gg * 16 + cc][nf * 4 + rr];
  }
  *(float4*)(out + (size_t)(m0 + mi) * KSZ + n4) = res;
}

extern "C" void kernel_launch(void* const* d_in, const int* in_sizes, int n_in,
                              void* d_out, int out_size, void* d_ws, size_t ws_size,
                              hipStream_t stream) {
  const float* x    = (const float*)d_in[0];
  const float* Wq   = (const float*)d_in[1];
  const float* Wk   = (const float*)d_in[2];
  const float* Wv   = (const float*)d_in[3];
  const float* kern = (const float*)d_in[4];
  float* out = (float*)d_out;

  u16* xb     = (u16*)d_ws;                          // 8.4 MB
  u16* Wt     = xb + (size_t)4096 * 1024;            // 6.3 MB
  u16* qkvT   = Wt + (size_t)3 * 1024 * 1024;        // 25.2 MB
  u16* headsB = qkvT + (size_t)3 * BB * HH * SS * KSZ;  // 8.4 MB
  u16* BpT    = headsB + (size_t)BB * HH * SS * KSZ;    // 0.13 MB

  prep_all<<<dim3(2880), 256, 0, stream>>>(x, Wq, Wk, Wv, kern, xb, Wt, BpT);
  proj_kernel<<<dim3(768), 512, 0, stream>>>(xb, Wt, qkvT);
  attn_kernel<<<dim3(512), 256, 0, stream>>>(qkvT, headsB);
  out_kernel<<<dim3(256), 256, 0, stream>>>(headsB, BpT, out);
}